// Round 18
// baseline (183.930 us; speedup 1.0000x reference)
//
#include <hip/hip_runtime.h>
#include <hip/hip_bf16.h>

// HeteroGCN: 3x SAGEConv(mean).
// R1-R8: CSR gather (no atomics), LDS-binning CSR build, bf16 MFMA GEMM with
//        K-concat + packed weights, bf16 feature tables.
// R9 (failed): gather-in-GEMM (2 lanes/row) -> 8% occupancy.
// R10-R13: idx-broadcast gather; fused setup+scatter; 4-5 dispatches.
// R14 (failed): CAPW=64 cell overflow. R15: CAPW=128, 173 us.
// R16 (failed, +8): 96KB all-W LDS -> 1 block/CU.
// R17 (neutral/-, measured): barrier-free L2-direct gemm = 65 us, MfmaUtil 9%,
//      occupancy 26% -> gemm is a latency-bound streamer; micro-variants dead.
// R18: MFMA fused INTO agg (reverse of R9): gather phase unchanged (16
//      lanes/node), means -> LDS (136-short pitch); waves 0-3 then MFMA the
//      32-row tile (self rows from global, W from L2, K-concat) and write C.
//      Kills the 75MB agg write + 77MB re-read + the whole gemm dispatch.
//      3 dispatches: setup_scatter -> bbuild -> fused_agg_gemm.

#define D 128
#define NG 100000
#define NT 100000
#define NSEG (NG + NT + NG)   // concatenated dst-node counters: gg | gt | tg

#define NBUCK 256
#define NPB   ((NSEG + NBUCK - 1) / NBUCK)   // 1172 seg-nodes per bucket
#define TILE  4096                            // edges per bscatter workgroup
#define CAP   8192                            // max edges per bucket (mean 5860, +30 sigma)
#define CAPW  128                             // max edges per (bucket, WG) cell (mean 48, +11.6 sigma)
#define LROW  136                             // LDS row pitch in shorts (16B-aligned, 2-way banks)

typedef __bf16 bf16x8 __attribute__((ext_vector_type(8)));
typedef float f32x16 __attribute__((ext_vector_type(16)));
typedef float v2f __attribute__((ext_vector_type(2)));

static __device__ __forceinline__ unsigned short f2bf(float f) {
    return __builtin_bit_cast(unsigned short, (__bf16)f);
}
static __device__ __forceinline__ float bflo(unsigned int v) {
    return __builtin_bit_cast(float, v << 16);
}
static __device__ __forceinline__ float bfhi(unsigned int v) {
    return __builtin_bit_cast(float, v & 0xffff0000u);
}

// ---------------- edge helpers ----------------
static __device__ __forceinline__ int edge_seg(
    int ge, const int* d0, int n0, const int* d1, int n1, const int* d2)
{
    if (ge < n0) return d0[ge];
    if (ge < n0 + n1) return NG + d1[ge - n0];
    return NG + NT + d2[ge - n0 - n1];
}
static __device__ __forceinline__ int edge_src(
    int ge, const int* s0, int n0, const int* s1, int n1, const int* s2)
{
    if (ge < n0) return s0[ge];
    if (ge < n0 + n1) return s1[ge - n0];
    return s2[ge - n0 - n1];
}

// ---------------- fused: bscatter (blocks [0,nWG)) + setup (rest) ----------------
#define CVT8 (((NG + 1) + (NT + 1)) * D / 8)
#define SETUP_ITEMS (CVT8 + 6144 + 4096 + 128 + 128)

__global__ __launch_bounds__(256) void setup_scatter_kernel(
    // bscatter args
    const int* __restrict__ s0, const int* __restrict__ d0, int n0,
    const int* __restrict__ s1, const int* __restrict__ d1, int n1,
    const int* __restrict__ s2, const int* __restrict__ d2, int nE,
    int* __restrict__ cellcnt, int2* __restrict__ binned, int nWG,
    // setup args
    const float* __restrict__ xg, const float* __restrict__ xt,
    unsigned short* __restrict__ og, unsigned short* __restrict__ ot,
    const float* __restrict__ Ws_gg, const float* __restrict__ Ws_tg,
    const float* __restrict__ Wn_gg, const float* __restrict__ Wn_tg,
    const float* __restrict__ Ws_gt, const float* __restrict__ Wn_gt,
    const float* __restrict__ b_gg, const float* __restrict__ b_tg,
    const float* __restrict__ b_gt,
    unsigned short* __restrict__ WpG, unsigned short* __restrict__ WpT,
    float* __restrict__ biasG, float* __restrict__ biasT)
{
    __shared__ int2 stage[TILE];                                  // 32 KiB
    __shared__ int hist[NBUCK], scn[NBUCK], lcur[NBUCK];
    const int t = threadIdx.x;

    if ((int)blockIdx.x < nWG) {
        // ---- bscatter body: LDS multi-split into deterministic cells ----
        hist[t] = 0;
        __syncthreads();

        const int base = blockIdx.x * TILE;
        int mseg[TILE / 256], msrc[TILE / 256];
#pragma unroll
        for (int j = 0; j < TILE / 256; ++j) {
            const int ge = base + j * 256 + t;
            if (ge < nE) {
                mseg[j] = edge_seg(ge, d0, n0, d1, n1, d2);
                msrc[j] = edge_src(ge, s0, n0, s1, n1, s2);
                atomicAdd(&hist[mseg[j] / NPB], 1);
            } else mseg[j] = -1;
        }
        __syncthreads();

        // cell count for bucket t (this WG)
        const int h = hist[t];
        cellcnt[(size_t)t * nWG + blockIdx.x] = min(h, CAPW);

        // exclusive scan of per-WG histogram (LDS reorder only)
        scn[t] = h;
        __syncthreads();
        for (int sh = 1; sh < NBUCK; sh <<= 1) {
            int u = (t >= sh) ? scn[t - sh] : 0;
            __syncthreads();
            scn[t] += u;
            __syncthreads();
        }
        const int excl = scn[t] - h;
        __syncthreads();
        scn[t] = excl;
        lcur[t] = excl;
        __syncthreads();

#pragma unroll
        for (int j = 0; j < TILE / 256; ++j) {
            if (mseg[j] >= 0) {
                const int b = mseg[j] / NPB;
                const int pos = atomicAdd(&lcur[b], 1);
                stage[pos] = make_int2(msrc[j], mseg[j]);
            }
        }
        __syncthreads();

        const int cnt = min(TILE, nE - base);
        for (int slot = t; slot < cnt; slot += 256) {
            const int2 pr = stage[slot];
            const int b = pr.y / NPB;
            const int pic = slot - scn[b];
            if (pic < CAPW)
                binned[((size_t)b * nWG + blockIdx.x) * CAPW + pic] = pr;
        }
        return;
    }

    // ---- setup body: bf16 tables (+zero row) | weight pack | bias fold ----
    const int gid = (blockIdx.x - nWG) * 256 + t;
    if (gid < CVT8) {
        const int ng8 = (NG + 1) * D / 8;
        const float* x; unsigned short* o; int j, nreal8;
        if (gid < ng8) { x = xg; o = og; j = gid;       nreal8 = NG * D / 8; }
        else           { x = xt; o = ot; j = gid - ng8; nreal8 = NT * D / 8; }
        uint4 v = make_uint4(0, 0, 0, 0);
        if (j < nreal8) {
            const float4 f0 = ((const float4*)x)[j * 2];
            const float4 f1 = ((const float4*)x)[j * 2 + 1];
            v.x = (unsigned int)f2bf(f0.x) | ((unsigned int)f2bf(f0.y) << 16);
            v.y = (unsigned int)f2bf(f0.z) | ((unsigned int)f2bf(f0.w) << 16);
            v.z = (unsigned int)f2bf(f1.x) | ((unsigned int)f2bf(f1.y) << 16);
            v.w = (unsigned int)f2bf(f1.z) | ((unsigned int)f2bf(f1.w) << 16);
        }
        ((uint4*)o)[j] = v;
        return;
    }
    const int g2 = gid - CVT8;
    if (g2 < 6144) {                        // gene pack: 24 kt * 4 nt * 64 lanes
        const int lane = g2 & 63, nt = (g2 >> 6) & 3, kt = g2 >> 8;
        const int n = nt * 32 + (lane & 31);
        const int kb = kt * 16 + (lane >> 5) * 8;
        unsigned int pk[4];
#pragma unroll
        for (int jj = 0; jj < 4; ++jj) {
            unsigned int w2 = 0;
#pragma unroll
            for (int h = 0; h < 2; ++h) {
                const int k = kb + jj * 2 + h;
                float w;
                if (k < 128)      w = Ws_gg[k * D + n] + Ws_tg[k * D + n];
                else if (k < 256) w = Wn_gg[(k - 128) * D + n];
                else              w = Wn_tg[(k - 256) * D + n];
                w2 |= ((unsigned int)f2bf(w)) << (16 * h);
            }
            pk[jj] = w2;
        }
        *(uint4*)(WpG + (size_t)g2 * 8) = make_uint4(pk[0], pk[1], pk[2], pk[3]);
    } else if (g2 < 6144 + 4096) {          // trait pack: 16 kt * 4 nt * 64 lanes
        const int g = g2 - 6144;
        const int lane = g & 63, nt = (g >> 6) & 3, kt = g >> 8;
        const int n = nt * 32 + (lane & 31);
        const int kb = kt * 16 + (lane >> 5) * 8;
        unsigned int pk[4];
#pragma unroll
        for (int jj = 0; jj < 4; ++jj) {
            unsigned int w2 = 0;
#pragma unroll
            for (int h = 0; h < 2; ++h) {
                const int k = kb + jj * 2 + h;
                const float w = (k < 128) ? Ws_gt[k * D + n] : Wn_gt[(k - 128) * D + n];
                w2 |= ((unsigned int)f2bf(w)) << (16 * h);
            }
            pk[jj] = w2;
        }
        *(uint4*)(WpT + (size_t)g * 8) = make_uint4(pk[0], pk[1], pk[2], pk[3]);
    } else if (g2 < 10240 + 128) {
        const int i = g2 - 10240;
        biasG[i] = b_gg[i] + b_tg[i];
    } else if (g2 < 10368 + 128) {
        const int i = g2 - 10368;
        biasT[i] = b_gt[i];
    }
}

// ---------------- bbuild: per-bucket counting sort from cells ----------------
__global__ __launch_bounds__(256) void bbuild_kernel(
    const int2* __restrict__ binned, const int* __restrict__ cellcnt, int nWG,
    int* __restrict__ off, int* __restrict__ dend, int* __restrict__ sorted)
{
    constexpr int CH = (NPB + 255) / 256;   // 5
    __shared__ int ldeg[NPB];
    __shared__ int loff[NPB];
    __shared__ int psum[256];
    const int t = threadIdx.x;
    const int b = blockIdx.x;
    const int n0 = b * NPB;
    const int NL = min(NSEG - n0, NPB);

    for (int i = t; i < NL; i += 256) ldeg[i] = 0;
    __syncthreads();

    for (int w = t; w < nWG; w += 256) {
        const int c = min(cellcnt[(size_t)b * nWG + w], CAPW);
        const int2* cell = binned + ((size_t)b * nWG + w) * CAPW;
        for (int i = 0; i < c; ++i)
            atomicAdd(&ldeg[cell[i].y - n0], 1);
    }
    __syncthreads();

    int s = 0;
#pragma unroll
    for (int k = 0; k < CH; ++k) {
        const int i = t * CH + k;
        if (i < NL) s += ldeg[i];
    }
    psum[t] = s;
    __syncthreads();
    for (int sh = 1; sh < 256; sh <<= 1) {
        int u = (t >= sh) ? psum[t - sh] : 0;
        __syncthreads();
        psum[t] += u;
        __syncthreads();
    }
    int run = psum[t] - s;
#pragma unroll
    for (int k = 0; k < CH; ++k) {
        const int i = t * CH + k;
        if (i < NL) { loff[i] = run; run += ldeg[i]; }
    }
    __syncthreads();

    const int ebase = b * CAP;
    for (int i = t; i < NL; i += 256) {
        off[n0 + i]  = ebase + loff[i];
        dend[n0 + i] = ebase + loff[i] + ldeg[i];
    }
    __syncthreads();

    for (int w = t; w < nWG; w += 256) {
        const int c = min(cellcnt[(size_t)b * nWG + w], CAPW);
        const int2* cell = binned + ((size_t)b * nWG + w) * CAPW;
        for (int i = 0; i < c; ++i) {
            const int2 pr = cell[i];
            const int slot = atomicAdd(&loff[pr.y - n0], 1);
            sorted[ebase + slot] = pr.x;
        }
    }
}

// ---------------- fused agg + GEMM ----------------
// 512 threads = 32 output rows/block (NG,NT % 32 == 0 -> no tails).
// Gather phase (all 8 waves, 16 lanes/node, idx-broadcast) writes bf16 means
// into LDS (pitch 136 shorts). Then waves 0-3 each MFMA one 32-col quadrant:
// self A-frags from global xb, mean A-frags from LDS, B-frags from L2 Wpack.
static __device__ __forceinline__ void gather_to_lds(
    const unsigned short* __restrict__ xb, const int* __restrict__ off,
    const int* __restrict__ dend, const int* __restrict__ sorted,
    int segbase, int tile, int t, unsigned short* lds, int zrow)
{
    const int g = t >> 4;          // node group 0..31
    const int l = t & 15;
    const int gb = (t & 63) & ~15; // group base lane within wave
    const int node = segbase + tile * 32 + g;
    const int s0 = off[node];
    const int s1 = dend[node];

    v2f A0 = (v2f){0.f, 0.f}, A1 = (v2f){0.f, 0.f};
    v2f A2 = (v2f){0.f, 0.f}, A3 = (v2f){0.f, 0.f};

    for (int e = s0; e < s1; e += 16) {
        const int cnt = min(s1 - e, 16);
        const int myidx = sorted[e + min(l, cnt - 1)];
#pragma unroll
        for (int j = 0; j < 16; j += 4) {
            if (j < cnt) {
                const int i0 = __shfl(myidx, gb + j, 64);
                const int i1 = (j + 1 < cnt) ? __shfl(myidx, gb + j + 1, 64) : zrow;
                const int i2 = (j + 2 < cnt) ? __shfl(myidx, gb + j + 2, 64) : zrow;
                const int i3 = (j + 3 < cnt) ? __shfl(myidx, gb + j + 3, 64) : zrow;
                const uint4 v0 = *(const uint4*)(xb + (size_t)i0 * D + l * 8);
                const uint4 v1 = *(const uint4*)(xb + (size_t)i1 * D + l * 8);
                const uint4 v2 = *(const uint4*)(xb + (size_t)i2 * D + l * 8);
                const uint4 v3 = *(const uint4*)(xb + (size_t)i3 * D + l * 8);
                A0 += (v2f){bflo(v0.x), bfhi(v0.x)};
                A1 += (v2f){bflo(v0.y), bfhi(v0.y)};
                A2 += (v2f){bflo(v0.z), bfhi(v0.z)};
                A3 += (v2f){bflo(v0.w), bfhi(v0.w)};
                A0 += (v2f){bflo(v1.x), bfhi(v1.x)};
                A1 += (v2f){bflo(v1.y), bfhi(v1.y)};
                A2 += (v2f){bflo(v1.z), bfhi(v1.z)};
                A3 += (v2f){bflo(v1.w), bfhi(v1.w)};
                A0 += (v2f){bflo(v2.x), bfhi(v2.x)};
                A1 += (v2f){bflo(v2.y), bfhi(v2.y)};
                A2 += (v2f){bflo(v2.z), bfhi(v2.z)};
                A3 += (v2f){bflo(v2.w), bfhi(v2.w)};
                A0 += (v2f){bflo(v3.x), bfhi(v3.x)};
                A1 += (v2f){bflo(v3.y), bfhi(v3.y)};
                A2 += (v2f){bflo(v3.z), bfhi(v3.z)};
                A3 += (v2f){bflo(v3.w), bfhi(v3.w)};
            }
        }
    }

    const float inv = 1.0f / (float)max(s1 - s0, 1);
    uint4 o;
    o.x = (unsigned int)f2bf(A0.x * inv) | ((unsigned int)f2bf(A0.y * inv) << 16);
    o.y = (unsigned int)f2bf(A1.x * inv) | ((unsigned int)f2bf(A1.y * inv) << 16);
    o.z = (unsigned int)f2bf(A2.x * inv) | ((unsigned int)f2bf(A2.y * inv) << 16);
    o.w = (unsigned int)f2bf(A3.x * inv) | ((unsigned int)f2bf(A3.y * inv) << 16);
    *(uint4*)(lds + (size_t)g * LROW + l * 8) = o;
}

__global__ __launch_bounds__(512) void fused_agg_gemm(
    const unsigned short* __restrict__ xbG, const unsigned short* __restrict__ xbT,
    const int* __restrict__ off, const int* __restrict__ dend,
    const int* __restrict__ sorted,
    const unsigned short* __restrict__ WpG, const unsigned short* __restrict__ WpT,
    const float* __restrict__ biasG, const float* __restrict__ biasT,
    float* __restrict__ outG, float* __restrict__ outT, int GB)
{
    __shared__ unsigned short MEAN[2][32 * LROW];   // 2 x 8.5 KiB
    const int t = threadIdx.x;
    const bool isG = (int)blockIdx.x < GB;
    const int tile = isG ? blockIdx.x : blockIdx.x - GB;

    // ---- gather phase (all 8 waves) ----
    if (isG) {
        gather_to_lds(xbG, off, dend, sorted, 0,       tile, t, MEAN[0], NG); // mean_gg
        gather_to_lds(xbT, off, dend, sorted, NG + NT, tile, t, MEAN[1], NT); // mean_tg
    } else {
        gather_to_lds(xbG, off, dend, sorted, NG,      tile, t, MEAN[0], NG); // mean_gt
    }
    __syncthreads();

    // ---- MFMA phase (waves 0-3, one 32-col quadrant each) ----
    const int wid = t >> 6;
    if (wid >= 4) return;
    const int lane = t & 63;
    const int lm = lane & 31, l5 = lane >> 5;
    const int nt = wid;
    const int m = tile * 32 + lm;

    const unsigned short* self  = isG ? xbG : xbT;
    const unsigned short* Wpack = isG ? WpG : WpT;
    const float* bias = isG ? biasG : biasT;
    float* out = isG ? outG : outT;
    const int nkt = isG ? 24 : 16;

    f32x16 acc;
#pragma unroll
    for (int q = 0; q < 4; ++q) {
        const float4 bq = *(const float4*)&bias[nt * 32 + 4 * l5 + 8 * q];
        acc[4 * q + 0] = bq.x; acc[4 * q + 1] = bq.y;
        acc[4 * q + 2] = bq.z; acc[4 * q + 3] = bq.w;
    }

    const unsigned short* ar = self + (size_t)m * D + l5 * 8;
    const unsigned short* wb = Wpack + (size_t)lane * 8 + (size_t)nt * 64 * 8;
#pragma unroll 1
    for (int kt = 0; kt < nkt; ++kt) {
        bf16x8 a;
        if (kt < 8)       a = *(const bf16x8*)(ar + kt * 16);
        else if (kt < 16) a = *(const bf16x8*)&MEAN[0][(size_t)lm * LROW + (kt - 8) * 16 + l5 * 8];
        else              a = *(const bf16x8*)&MEAN[1][(size_t)lm * LROW + (kt - 16) * 16 + l5 * 8];
        const bf16x8 b = *(const bf16x8*)(wb + (size_t)kt * 4 * 64 * 8);
        acc = __builtin_amdgcn_mfma_f32_32x32x16_bf16(b, a, acc, 0, 0, 0);
    }

    float* p = out + (size_t)m * D + nt * 32 + 4 * l5;
    *(float4*)(p + 0)  = make_float4(acc[0],  acc[1],  acc[2],  acc[3]);
    *(float4*)(p + 8)  = make_float4(acc[4],  acc[5],  acc[6],  acc[7]);
    *(float4*)(p + 16) = make_float4(acc[8],  acc[9],  acc[10], acc[11]);
    *(float4*)(p + 24) = make_float4(acc[12], acc[13], acc[14], acc[15]);
}

extern "C" void kernel_launch(void* const* d_in, const int* in_sizes, int n_in,
                              void* d_out, int out_size, void* d_ws, size_t ws_size,
                              hipStream_t stream)
{
    const float* x_gene  = (const float*)d_in[0];
    const float* x_trait = (const float*)d_in[1];
    const int* src_gg = (const int*)d_in[2];
    const int* dst_gg = (const int*)d_in[3];
    const int* src_gt = (const int*)d_in[4];
    const int* dst_gt = (const int*)d_in[5];
    const int* src_tg = (const int*)d_in[6];
    const int* dst_tg = (const int*)d_in[7];
    const float* Wn_gg = (const float*)d_in[8];
    const float* Ws_gg = (const float*)d_in[9];
    const float* b_gg  = (const float*)d_in[10];
    const float* Wn_gt = (const float*)d_in[11];
    const float* Ws_gt = (const float*)d_in[12];
    const float* b_gt  = (const float*)d_in[13];
    const float* Wn_tg = (const float*)d_in[14];
    const float* Ws_tg = (const float*)d_in[15];
    const float* b_tg  = (const float*)d_in[16];

    const int nE_gg = in_sizes[2];
    const int nE_gt = in_sizes[4];
    const int nE_tg = in_sizes[6];
    const int nE_total = nE_gg + nE_gt + nE_tg;
    const int nWG = (nE_total + TILE - 1) / TILE;

    float* out_gene  = (float*)d_out;
    float* out_trait = (float*)d_out + (size_t)NG * D;

    // ws: xb_gene[(NG+1)*D] | xb_trait[(NT+1)*D] | WpG | WpT | biasG | biasT |
    //   off[NSEG] | dend[NSEG] | sorted[NBUCK*CAP] | cellcnt[NBUCK*nWG] |
    //   binned[NBUCK*nWG*CAPW]
    unsigned short* xb_gene  = (unsigned short*)d_ws;
    unsigned short* xb_trait = xb_gene + (size_t)(NG + 1) * D;
    char* p = (char*)(xb_trait + (size_t)(NT + 1) * D);
    unsigned short* WpG = (unsigned short*)p;  p += 24 * 4 * 64 * 8 * sizeof(unsigned short);
    unsigned short* WpT = (unsigned short*)p;  p += 16 * 4 * 64 * 8 * sizeof(unsigned short);
    float* biasG = (float*)p;                  p += D * sizeof(float);
    float* biasT = (float*)p;                  p += D * sizeof(float);
    int* off     = (int*)p;                    p += (size_t)NSEG * sizeof(int);
    int* dend    = (int*)p;                    p += (size_t)NSEG * sizeof(int);
    int* sorted  = (int*)p;                    p += (size_t)NBUCK * CAP * sizeof(int);
    int* cellcnt = (int*)p;                    p += (size_t)NBUCK * nWG * sizeof(int);
    int2* binned = (int2*)p;

    // 1) fused: edge binning into cells (blocks [0,nWG)) + cvt + weight pack
    const int setup_blocks = (SETUP_ITEMS + 255) / 256;
    setup_scatter_kernel<<<nWG + setup_blocks, 256, 0, stream>>>(
        src_gg, dst_gg, nE_gg, src_gt, dst_gt, nE_gt, src_tg, dst_tg,
        nE_total, cellcnt, binned, nWG,
        x_gene, x_trait, xb_gene, xb_trait,
        Ws_gg, Ws_tg, Wn_gg, Wn_tg, Ws_gt, Wn_gt, b_gg, b_tg, b_gt,
        WpG, WpT, biasG, biasT);

    // 2) per-bucket counting sort -> off/dend/sorted
    bbuild_kernel<<<NBUCK, 256, 0, stream>>>(binned, cellcnt, nWG, off, dend, sorted);

    // 3) fused gather-mean + MFMA + C-write (gene tiles then trait tiles)
    const int GBb = NG / 32;   // 3125, exact
    const int TBb = NT / 32;   // 3125, exact
    fused_agg_gemm<<<GBb + TBb, 512, 0, stream>>>(
        xb_gene, xb_trait, off, dend, sorted, WpG, WpT, biasG, biasT,
        out_gene, out_trait, GBb);
}

// Round 19
// 174.586 us; speedup vs baseline: 1.0535x; 1.0535x over previous
//
#include <hip/hip_runtime.h>
#include <hip/hip_bf16.h>

// HeteroGCN: 3x SAGEConv(mean).
// R1-R8: CSR gather (no atomics), LDS-binning CSR build, bf16 MFMA GEMM with
//        K-concat + packed weights, bf16 feature tables.
// R9 (failed): gather-in-GEMM (2 lanes/row) -> 8% occupancy.
// R10-R13: idx-broadcast gather; fused setup+scatter; 4-5 dispatches.
// R14 (failed): CAPW=64 cell overflow. R15: CAPW=128 -> 173 us (BEST).
// R16 (failed, +8): 96KB all-W LDS -> 1 block/CU.
// R17 (neutral): barrier-free L2-direct gemm = 65us, latency-bound streamer.
// R18 (failed, +11): MFMA fused into agg -> serial phases, half-block idle.
// R19: REVERT to R15 exactly. Component floors measured: agg 65 (random-gather
//      service floor), gemm ~57 (latency-bound, variant-resistant), setup 27
//      (input BW floor), bbuild 7. This is the composed roofline.

#define D 128
#define NG 100000
#define NT 100000
#define NSEG (NG + NT + NG)   // concatenated dst-node counters: gg | gt | tg

#define NBUCK 256
#define NPB   ((NSEG + NBUCK - 1) / NBUCK)   // 1172 seg-nodes per bucket
#define TILE  4096                            // edges per bscatter workgroup
#define CAP   8192                            // max edges per bucket (mean 5860, +30 sigma)
#define CAPW  128                             // max edges per (bucket, WG) cell (mean 48, +11.6 sigma)

typedef __bf16 bf16x8 __attribute__((ext_vector_type(8)));
typedef float f32x16 __attribute__((ext_vector_type(16)));
typedef float v2f __attribute__((ext_vector_type(2)));

static __device__ __forceinline__ unsigned short f2bf(float f) {
    return __builtin_bit_cast(unsigned short, (__bf16)f);
}
static __device__ __forceinline__ float bflo(unsigned int v) {
    return __builtin_bit_cast(float, v << 16);
}
static __device__ __forceinline__ float bfhi(unsigned int v) {
    return __builtin_bit_cast(float, v & 0xffff0000u);
}

// ---------------- edge helpers ----------------
static __device__ __forceinline__ int edge_seg(
    int ge, const int* d0, int n0, const int* d1, int n1, const int* d2)
{
    if (ge < n0) return d0[ge];
    if (ge < n0 + n1) return NG + d1[ge - n0];
    return NG + NT + d2[ge - n0 - n1];
}
static __device__ __forceinline__ int edge_src(
    int ge, const int* s0, int n0, const int* s1, int n1, const int* s2)
{
    if (ge < n0) return s0[ge];
    if (ge < n0 + n1) return s1[ge - n0];
    return s2[ge - n0 - n1];
}

// ---------------- fused: bscatter (blocks [0,nWG)) + setup (rest) ----------------
#define CVT8 (((NG + 1) + (NT + 1)) * D / 8)
#define SETUP_ITEMS (CVT8 + 6144 + 4096 + 128 + 128)

__global__ __launch_bounds__(256) void setup_scatter_kernel(
    // bscatter args
    const int* __restrict__ s0, const int* __restrict__ d0, int n0,
    const int* __restrict__ s1, const int* __restrict__ d1, int n1,
    const int* __restrict__ s2, const int* __restrict__ d2, int nE,
    int* __restrict__ cellcnt, int2* __restrict__ binned, int nWG,
    // setup args
    const float* __restrict__ xg, const float* __restrict__ xt,
    unsigned short* __restrict__ og, unsigned short* __restrict__ ot,
    const float* __restrict__ Ws_gg, const float* __restrict__ Ws_tg,
    const float* __restrict__ Wn_gg, const float* __restrict__ Wn_tg,
    const float* __restrict__ Ws_gt, const float* __restrict__ Wn_gt,
    const float* __restrict__ b_gg, const float* __restrict__ b_tg,
    const float* __restrict__ b_gt,
    unsigned short* __restrict__ WpG, unsigned short* __restrict__ WpT,
    float* __restrict__ biasG, float* __restrict__ biasT)
{
    __shared__ int2 stage[TILE];                                  // 32 KiB
    __shared__ int hist[NBUCK], scn[NBUCK], lcur[NBUCK];
    const int t = threadIdx.x;

    if ((int)blockIdx.x < nWG) {
        // ---- bscatter body: LDS multi-split into deterministic cells ----
        hist[t] = 0;
        __syncthreads();

        const int base = blockIdx.x * TILE;
        int mseg[TILE / 256], msrc[TILE / 256];
#pragma unroll
        for (int j = 0; j < TILE / 256; ++j) {
            const int ge = base + j * 256 + t;
            if (ge < nE) {
                mseg[j] = edge_seg(ge, d0, n0, d1, n1, d2);
                msrc[j] = edge_src(ge, s0, n0, s1, n1, s2);
                atomicAdd(&hist[mseg[j] / NPB], 1);
            } else mseg[j] = -1;
        }
        __syncthreads();

        // cell count for bucket t (this WG) -- no global atomics needed
        const int h = hist[t];
        cellcnt[(size_t)t * nWG + blockIdx.x] = min(h, CAPW);

        // exclusive scan of per-WG histogram (for LDS reorder only)
        scn[t] = h;
        __syncthreads();
        for (int sh = 1; sh < NBUCK; sh <<= 1) {
            int u = (t >= sh) ? scn[t - sh] : 0;
            __syncthreads();
            scn[t] += u;
            __syncthreads();
        }
        const int excl = scn[t] - h;
        __syncthreads();
        scn[t] = excl;
        lcur[t] = excl;
        __syncthreads();

#pragma unroll
        for (int j = 0; j < TILE / 256; ++j) {
            if (mseg[j] >= 0) {
                const int b = mseg[j] / NPB;
                const int pos = atomicAdd(&lcur[b], 1);
                stage[pos] = make_int2(msrc[j], mseg[j]);
            }
        }
        __syncthreads();

        const int cnt = min(TILE, nE - base);
        for (int slot = t; slot < cnt; slot += 256) {
            const int2 pr = stage[slot];
            const int b = pr.y / NPB;
            const int pic = slot - scn[b];     // position within this WG's cell
            if (pic < CAPW)
                binned[((size_t)b * nWG + blockIdx.x) * CAPW + pic] = pr;
        }
        return;
    }

    // ---- setup body: bf16 tables (+zero row) | weight pack | bias fold ----
    const int gid = (blockIdx.x - nWG) * 256 + t;
    if (gid < CVT8) {
        const int ng8 = (NG + 1) * D / 8;
        const float* x; unsigned short* o; int j, nreal8;
        if (gid < ng8) { x = xg; o = og; j = gid;       nreal8 = NG * D / 8; }
        else           { x = xt; o = ot; j = gid - ng8; nreal8 = NT * D / 8; }
        uint4 v = make_uint4(0, 0, 0, 0);
        if (j < nreal8) {
            const float4 f0 = ((const float4*)x)[j * 2];
            const float4 f1 = ((const float4*)x)[j * 2 + 1];
            v.x = (unsigned int)f2bf(f0.x) | ((unsigned int)f2bf(f0.y) << 16);
            v.y = (unsigned int)f2bf(f0.z) | ((unsigned int)f2bf(f0.w) << 16);
            v.z = (unsigned int)f2bf(f1.x) | ((unsigned int)f2bf(f1.y) << 16);
            v.w = (unsigned int)f2bf(f1.z) | ((unsigned int)f2bf(f1.w) << 16);
        }
        ((uint4*)o)[j] = v;
        return;
    }
    const int g2 = gid - CVT8;
    if (g2 < 6144) {                        // gene pack: 24 kt * 4 nt * 64 lanes
        const int lane = g2 & 63, nt = (g2 >> 6) & 3, kt = g2 >> 8;
        const int n = nt * 32 + (lane & 31);
        const int kb = kt * 16 + (lane >> 5) * 8;
        unsigned int pk[4];
#pragma unroll
        for (int jj = 0; jj < 4; ++jj) {
            unsigned int w2 = 0;
#pragma unroll
            for (int h = 0; h < 2; ++h) {
                const int k = kb + jj * 2 + h;
                float w;
                if (k < 128)      w = Ws_gg[k * D + n] + Ws_tg[k * D + n];
                else if (k < 256) w = Wn_gg[(k - 128) * D + n];
                else              w = Wn_tg[(k - 256) * D + n];
                w2 |= ((unsigned int)f2bf(w)) << (16 * h);
            }
            pk[jj] = w2;
        }
        *(uint4*)(WpG + (size_t)g2 * 8) = make_uint4(pk[0], pk[1], pk[2], pk[3]);
    } else if (g2 < 6144 + 4096) {          // trait pack: 16 kt * 4 nt * 64 lanes
        const int g = g2 - 6144;
        const int lane = g & 63, nt = (g >> 6) & 3, kt = g >> 8;
        const int n = nt * 32 + (lane & 31);
        const int kb = kt * 16 + (lane >> 5) * 8;
        unsigned int pk[4];
#pragma unroll
        for (int jj = 0; jj < 4; ++jj) {
            unsigned int w2 = 0;
#pragma unroll
            for (int h = 0; h < 2; ++h) {
                const int k = kb + jj * 2 + h;
                const float w = (k < 128) ? Ws_gt[k * D + n] : Wn_gt[(k - 128) * D + n];
                w2 |= ((unsigned int)f2bf(w)) << (16 * h);
            }
            pk[jj] = w2;
        }
        *(uint4*)(WpT + (size_t)g * 8) = make_uint4(pk[0], pk[1], pk[2], pk[3]);
    } else if (g2 < 10240 + 128) {
        const int i = g2 - 10240;
        biasG[i] = b_gg[i] + b_tg[i];
    } else if (g2 < 10368 + 128) {
        const int i = g2 - 10368;
        biasT[i] = b_gt[i];
    }
}

// ---------------- bbuild: per-bucket counting sort from cells ----------------
__global__ __launch_bounds__(256) void bbuild_kernel(
    const int2* __restrict__ binned, const int* __restrict__ cellcnt, int nWG,
    int* __restrict__ off, int* __restrict__ dend, int* __restrict__ sorted)
{
    constexpr int CH = (NPB + 255) / 256;   // 5
    __shared__ int ldeg[NPB];
    __shared__ int loff[NPB];
    __shared__ int psum[256];
    const int t = threadIdx.x;
    const int b = blockIdx.x;
    const int n0 = b * NPB;
    const int NL = min(NSEG - n0, NPB);

    for (int i = t; i < NL; i += 256) ldeg[i] = 0;
    __syncthreads();

    // phase 1: per-node degree from this bucket's cells
    for (int w = t; w < nWG; w += 256) {
        const int c = min(cellcnt[(size_t)b * nWG + w], CAPW);
        const int2* cell = binned + ((size_t)b * nWG + w) * CAPW;
        for (int i = 0; i < c; ++i)
            atomicAdd(&ldeg[cell[i].y - n0], 1);
    }
    __syncthreads();

    // phase 2: block-wide exclusive scan over NL node degrees
    int s = 0;
#pragma unroll
    for (int k = 0; k < CH; ++k) {
        const int i = t * CH + k;
        if (i < NL) s += ldeg[i];
    }
    psum[t] = s;
    __syncthreads();
    for (int sh = 1; sh < 256; sh <<= 1) {
        int u = (t >= sh) ? psum[t - sh] : 0;
        __syncthreads();
        psum[t] += u;
        __syncthreads();
    }
    int run = psum[t] - s;
#pragma unroll
    for (int k = 0; k < CH; ++k) {
        const int i = t * CH + k;
        if (i < NL) { loff[i] = run; run += ldeg[i]; }
    }
    __syncthreads();

    const int ebase = b * CAP;
    for (int i = t; i < NL; i += 256) {
        off[n0 + i]  = ebase + loff[i];
        dend[n0 + i] = ebase + loff[i] + ldeg[i];
    }
    __syncthreads();

    // phase 3: scatter cells into per-node-contiguous sorted[]
    for (int w = t; w < nWG; w += 256) {
        const int c = min(cellcnt[(size_t)b * nWG + w], CAPW);
        const int2* cell = binned + ((size_t)b * nWG + w) * CAPW;
        for (int i = 0; i < c; ++i) {
            const int2 pr = cell[i];
            const int slot = atomicAdd(&loff[pr.y - n0], 1);
            sorted[ebase + slot] = pr.x;
        }
    }
}

// ---------------- aggregation: idx-broadcast gather, packed f32 accumulate ----------------
__global__ __launch_bounds__(256) void agg_all_kernel(
    const unsigned short* __restrict__ xg, const unsigned short* __restrict__ xt,
    const int* __restrict__ off, const int* __restrict__ dend,
    const int* __restrict__ sorted,
    unsigned short* __restrict__ aggA, unsigned short* __restrict__ aggC,
    unsigned short* __restrict__ aggB)
{
    const int t = threadIdx.x;
    const int node = blockIdx.x * 16 + (t >> 4);
    if (node >= NSEG) return;
    const int l = t & 15;
    const int gb = (t & 63) & ~15;   // group base lane within wave
    const int s0 = off[node];
    const int s1 = dend[node];

    const unsigned short* xb;
    unsigned short* out;
    int local, zrow;
    if (node < NG)           { xb = xg; out = aggA; local = node;           zrow = NG; }
    else if (node < NG + NT) { xb = xg; out = aggC; local = node - NG;      zrow = NG; }
    else                     { xb = xt; out = aggB; local = node - NG - NT; zrow = NT; }

    v2f A0 = (v2f){0.f, 0.f}, A1 = (v2f){0.f, 0.f};
    v2f A2 = (v2f){0.f, 0.f}, A3 = (v2f){0.f, 0.f};

    for (int e = s0; e < s1; e += 16) {
        const int cnt = min(s1 - e, 16);
        const int myidx = sorted[e + min(l, cnt - 1)];
#pragma unroll
        for (int j = 0; j < 16; j += 4) {
            if (j < cnt) {
                const int i0 = __shfl(myidx, gb + j, 64);
                const int i1 = (j + 1 < cnt) ? __shfl(myidx, gb + j + 1, 64) : zrow;
                const int i2 = (j + 2 < cnt) ? __shfl(myidx, gb + j + 2, 64) : zrow;
                const int i3 = (j + 3 < cnt) ? __shfl(myidx, gb + j + 3, 64) : zrow;
                const uint4 v0 = *(const uint4*)(xb + (size_t)i0 * D + l * 8);
                const uint4 v1 = *(const uint4*)(xb + (size_t)i1 * D + l * 8);
                const uint4 v2 = *(const uint4*)(xb + (size_t)i2 * D + l * 8);
                const uint4 v3 = *(const uint4*)(xb + (size_t)i3 * D + l * 8);
                A0 += (v2f){bflo(v0.x), bfhi(v0.x)};
                A1 += (v2f){bflo(v0.y), bfhi(v0.y)};
                A2 += (v2f){bflo(v0.z), bfhi(v0.z)};
                A3 += (v2f){bflo(v0.w), bfhi(v0.w)};
                A0 += (v2f){bflo(v1.x), bfhi(v1.x)};
                A1 += (v2f){bflo(v1.y), bfhi(v1.y)};
                A2 += (v2f){bflo(v1.z), bfhi(v1.z)};
                A3 += (v2f){bflo(v1.w), bfhi(v1.w)};
                A0 += (v2f){bflo(v2.x), bfhi(v2.x)};
                A1 += (v2f){bflo(v2.y), bfhi(v2.y)};
                A2 += (v2f){bflo(v2.z), bfhi(v2.z)};
                A3 += (v2f){bflo(v2.w), bfhi(v2.w)};
                A0 += (v2f){bflo(v3.x), bfhi(v3.x)};
                A1 += (v2f){bflo(v3.y), bfhi(v3.y)};
                A2 += (v2f){bflo(v3.z), bfhi(v3.z)};
                A3 += (v2f){bflo(v3.w), bfhi(v3.w)};
            }
        }
    }

    const float inv = 1.0f / (float)max(s1 - s0, 1);
    uint4 o;
    o.x = (unsigned int)f2bf(A0.x * inv) | ((unsigned int)f2bf(A0.y * inv) << 16);
    o.y = (unsigned int)f2bf(A1.x * inv) | ((unsigned int)f2bf(A1.y * inv) << 16);
    o.z = (unsigned int)f2bf(A2.x * inv) | ((unsigned int)f2bf(A2.y * inv) << 16);
    o.w = (unsigned int)f2bf(A3.x * inv) | ((unsigned int)f2bf(A3.y * inv) << 16);
    *(uint4*)(out + (size_t)local * D + l * 8) = o;
}

// ---------------- MFMA GEMM, both outputs in one launch (8 waves/block) ----------------
__global__ __launch_bounds__(512) void gemm_all(
    const unsigned short* __restrict__ xbG, const unsigned short* __restrict__ xbT,
    const unsigned short* __restrict__ aggA, const unsigned short* __restrict__ aggB,
    const unsigned short* __restrict__ aggC,
    const unsigned short* __restrict__ WpG, const unsigned short* __restrict__ WpT,
    const float* __restrict__ biasG, const float* __restrict__ biasT,
    float* __restrict__ outG, float* __restrict__ outT, int GB)
{
    __shared__ unsigned short WL[8 * 4 * 64 * 8];   // 32 KiB: one source slice
    const int t = threadIdx.x;
    const int wid = t >> 6, lane = t & 63;
    const int lm = lane & 31, l5 = lane >> 5;

    const bool isG = (int)blockIdx.x < GB;
    const int bloc = isG ? blockIdx.x : blockIdx.x - GB;
    const int M = isG ? NG : NT;
    const int nsrc = isG ? 3 : 2;
    const unsigned short* A0 = isG ? xbG : xbT;
    const unsigned short* A1 = isG ? aggA : aggC;
    const unsigned short* A2 = aggB;
    const unsigned short* Wpack = isG ? WpG : WpT;
    const float* bias = isG ? biasG : biasT;
    float* out = isG ? outG : outT;

    const int tile = bloc * 8 + wid;
    const bool active = tile * 32 < M;
    const int m = tile * 32 + lm;

    f32x16 acc[4];
    if (active) {
#pragma unroll
        for (int nt = 0; nt < 4; ++nt) {
#pragma unroll
            for (int q = 0; q < 4; ++q) {
                const float4 bq = *(const float4*)&bias[nt * 32 + 4 * l5 + 8 * q];
                acc[nt][4 * q + 0] = bq.x; acc[nt][4 * q + 1] = bq.y;
                acc[nt][4 * q + 2] = bq.z; acc[nt][4 * q + 3] = bq.w;
            }
        }
    }

    const uint4* wg = (const uint4*)Wpack;
    uint4* wl = (uint4*)WL;

#pragma unroll 1
    for (int s = 0; s < nsrc; ++s) {
        __syncthreads();
        wl[t]        = wg[(size_t)s * 2048 + t];
        wl[t + 512]  = wg[(size_t)s * 2048 + t + 512];
        wl[t + 1024] = wg[(size_t)s * 2048 + t + 1024];
        wl[t + 1536] = wg[(size_t)s * 2048 + t + 1536];
        __syncthreads();
        if (!active) continue;
        const unsigned short* ag = (s == 0) ? A0 : ((s == 1) ? A1 : A2);
        const unsigned short* ar = ag + (size_t)m * D + l5 * 8;
#pragma unroll
        for (int kt = 0; kt < 8; ++kt) {
            const bf16x8 a = *(const bf16x8*)(ar + kt * 16);
#pragma unroll
            for (int nt = 0; nt < 4; ++nt) {
                const bf16x8 b = *(const bf16x8*)&WL[((kt * 4 + nt) * 64 + lane) * 8];
                acc[nt] = __builtin_amdgcn_mfma_f32_32x32x16_bf16(b, a, acc[nt], 0, 0, 0);
            }
        }
    }

    if (active) {
        float* orow = out + (size_t)m * D;
#pragma unroll
        for (int nt = 0; nt < 4; ++nt) {
            float* p = orow + nt * 32 + 4 * l5;
            *(float4*)(p + 0)  = make_float4(acc[nt][0],  acc[nt][1],  acc[nt][2],  acc[nt][3]);
            *(float4*)(p + 8)  = make_float4(acc[nt][4],  acc[nt][5],  acc[nt][6],  acc[nt][7]);
            *(float4*)(p + 16) = make_float4(acc[nt][8],  acc[nt][9],  acc[nt][10], acc[nt][11]);
            *(float4*)(p + 24) = make_float4(acc[nt][12], acc[nt][13], acc[nt][14], acc[nt][15]);
        }
    }
}

extern "C" void kernel_launch(void* const* d_in, const int* in_sizes, int n_in,
                              void* d_out, int out_size, void* d_ws, size_t ws_size,
                              hipStream_t stream)
{
    const float* x_gene  = (const float*)d_in[0];
    const float* x_trait = (const float*)d_in[1];
    const int* src_gg = (const int*)d_in[2];
    const int* dst_gg = (const int*)d_in[3];
    const int* src_gt = (const int*)d_in[4];
    const int* dst_gt = (const int*)d_in[5];
    const int* src_tg = (const int*)d_in[6];
    const int* dst_tg = (const int*)d_in[7];
    const float* Wn_gg = (const float*)d_in[8];
    const float* Ws_gg = (const float*)d_in[9];
    const float* b_gg  = (const float*)d_in[10];
    const float* Wn_gt = (const float*)d_in[11];
    const float* Ws_gt = (const float*)d_in[12];
    const float* b_gt  = (const float*)d_in[13];
    const float* Wn_tg = (const float*)d_in[14];
    const float* Ws_tg = (const float*)d_in[15];
    const float* b_tg  = (const float*)d_in[16];

    const int nE_gg = in_sizes[2];
    const int nE_gt = in_sizes[4];
    const int nE_tg = in_sizes[6];
    const int nE_total = nE_gg + nE_gt + nE_tg;
    const int nWG = (nE_total + TILE - 1) / TILE;

    float* out_gene  = (float*)d_out;
    float* out_trait = (float*)d_out + (size_t)NG * D;

    // ws (~236 MB): xb_gene[(NG+1)*D] | xb_trait[(NT+1)*D] | aggA | aggB | aggC |
    //   WpG | WpT | biasG | biasT | off[NSEG] | dend[NSEG] |
    //   sorted[NBUCK*CAP] | cellcnt[NBUCK*nWG] | binned[NBUCK*nWG*CAPW]
    unsigned short* xb_gene  = (unsigned short*)d_ws;
    unsigned short* xb_trait = xb_gene + (size_t)(NG + 1) * D;
    unsigned short* aggA = xb_trait + (size_t)(NT + 1) * D;
    unsigned short* aggB = aggA + (size_t)NG * D;
    unsigned short* aggC = aggB + (size_t)NG * D;
    char* p = (char*)(aggC + (size_t)NT * D);
    unsigned short* WpG = (unsigned short*)p;  p += 24 * 4 * 64 * 8 * sizeof(unsigned short);
    unsigned short* WpT = (unsigned short*)p;  p += 16 * 4 * 64 * 8 * sizeof(unsigned short);
    float* biasG = (float*)p;                  p += D * sizeof(float);
    float* biasT = (float*)p;                  p += D * sizeof(float);
    int* off     = (int*)p;                    p += (size_t)NSEG * sizeof(int);
    int* dend    = (int*)p;                    p += (size_t)NSEG * sizeof(int);
    int* sorted  = (int*)p;                    p += (size_t)NBUCK * CAP * sizeof(int);
    int* cellcnt = (int*)p;                    p += (size_t)NBUCK * nWG * sizeof(int);
    int2* binned = (int2*)p;

    // 1) fused: edge binning into cells (blocks [0,nWG)) + cvt + weight pack
    const int setup_blocks = (SETUP_ITEMS + 255) / 256;
    setup_scatter_kernel<<<nWG + setup_blocks, 256, 0, stream>>>(
        src_gg, dst_gg, nE_gg, src_gt, dst_gt, nE_gt, src_tg, dst_tg,
        nE_total, cellcnt, binned, nWG,
        x_gene, x_trait, xb_gene, xb_trait,
        Ws_gg, Ws_tg, Wn_gg, Wn_tg, Ws_gt, Wn_gt, b_gg, b_tg, b_gt,
        WpG, WpT, biasG, biasT);

    // 2) per-bucket counting sort -> off/dend/sorted
    bbuild_kernel<<<NBUCK, 256, 0, stream>>>(binned, cellcnt, nWG, off, dend, sorted);

    // 3) fused aggregation over all 300k dst nodes (gg->aggA, gt->aggC, tg->aggB)
    agg_all_kernel<<<(NSEG + 15) / 16, 256, 0, stream>>>(
        xb_gene, xb_trait, off, dend, sorted, aggA, aggC, aggB);

    // 4) both output GEMMs in one launch (512-thread blocks, 8 waves)
    const int GBb = ((NG + 31) / 32 + 7) / 8;   // 391
    const int TBb = ((NT + 31) / 32 + 7) / 8;   // 391
    gemm_all<<<GBb + TBb, 512, 0, stream>>>(
        xb_gene, xb_trait, aggA, aggB, aggC, WpG, WpT, biasG, biasT,
        out_gene, out_trait, GBb);
}